// Round 1
// baseline (204.677 us; speedup 1.0000x reference)
//
#include <hip/hip_runtime.h>

// LengthRegulator: B=32, P=1024, D=384, T=max_length=3072 (fixed shapes).
// out[b,t,:] = x[b, idx, :] where idx = searchsorted(cumsum(dur[b]), t, 'right'),
// zeroed for t >= min(total_b, T). Second output: output_lengths (32 ints,
// stored as float32 in the tail of d_out since the flat buffer is read as f32).

#define BB 32
#define PP 1024
#define DD 384
#define TT 3072

__global__ __launch_bounds__(256) void lr_scan_idx_kernel(
    const int* __restrict__ dur, int* __restrict__ idx_map,
    float* __restrict__ len_out)
{
    __shared__ int csum[PP];
    __shared__ int wtot[4];
    const int b    = blockIdx.x;
    const int tid  = threadIdx.x;
    const int lane = tid & 63;
    const int wave = tid >> 6;

    // Each thread scans 4 consecutive durations (int4, 16B coalesced).
    int4 d = ((const int4*)(dur + b * PP))[tid];
    int s0 = d.x;
    int s1 = s0 + d.y;
    int s2 = s1 + d.z;
    int s3 = s2 + d.w;

    // Inclusive wave-scan of per-thread sums (64-lane shfl_up).
    int wsum = s3;
    #pragma unroll
    for (int off = 1; off < 64; off <<= 1) {
        int v = __shfl_up(wsum, off, 64);
        if (lane >= off) wsum += v;
    }
    if (lane == 63) wtot[wave] = wsum;
    __syncthreads();

    int woff = 0;
    for (int w = 0; w < wave; ++w) woff += wtot[w];
    const int pre = woff + wsum - s3;  // exclusive prefix for this thread's 4 elems

    csum[tid * 4 + 0] = pre + s0;
    csum[tid * 4 + 1] = pre + s1;
    csum[tid * 4 + 2] = pre + s2;
    csum[tid * 4 + 3] = pre + s3;
    __syncthreads();

    const int total  = csum[PP - 1];
    const int outlen = total < TT ? total : TT;
    if (tid == 0) len_out[b] = (float)outlen;

    // idx = searchsorted(csum, t, side='right') = #elements <= t.
    // For t < outlen <= total, result is <= PP-1 (clip is a no-op).
    for (int t = tid; t < TT; t += 256) {
        int m = -1;
        if (t < outlen) {
            int lo = 0, hi = PP;
            while (lo < hi) {
                int mid = (lo + hi) >> 1;
                if (csum[mid] <= t) lo = mid + 1; else hi = mid;
            }
            m = lo;
        }
        idx_map[b * TT + t] = m;
    }
}

// 384 threads = 4 rows x 96 float4/row. grid = (TT/4, BB).
__global__ __launch_bounds__(384) void lr_gather_kernel(
    const float* __restrict__ x, const int* __restrict__ idx_map,
    float* __restrict__ out)
{
    const int j   = threadIdx.x;
    const int lr  = j / 96;          // 0..3 local row
    const int c   = j - lr * 96;     // 0..95 float4 within row
    const int b   = blockIdx.y;
    const int t   = blockIdx.x * 4 + lr;
    const int row = b * TT + t;

    const int m = idx_map[row];      // broadcast across the row's 96 threads
    float4 v = make_float4(0.f, 0.f, 0.f, 0.f);
    if (m >= 0) {
        v = ((const float4*)(x + ((size_t)b * PP + m) * DD))[c];
    }
    ((float4*)out)[(size_t)row * 96 + c] = v;
}

extern "C" void kernel_launch(void* const* d_in, const int* in_sizes, int n_in,
                              void* d_out, int out_size, void* d_ws, size_t ws_size,
                              hipStream_t stream) {
    const float* x   = (const float*)d_in[0];
    const int*   dur = (const int*)d_in[1];
    // d_in[2] = max_length (device scalar) — value 3072, baked into TT.

    float* out     = (float*)d_out;
    float* len_out = out + (size_t)BB * TT * DD;   // 32 lengths in the tail
    int*   idx_map = (int*)d_ws;                   // BB*TT ints = 384 KiB

    lr_scan_idx_kernel<<<BB, 256, 0, stream>>>(dur, idx_map, len_out);
    lr_gather_kernel<<<dim3(TT / 4, BB), 384, 0, stream>>>(x, idx_map, out);
}

// Round 2
// 191.572 us; speedup vs baseline: 1.0684x; 1.0684x over previous
//
#include <hip/hip_runtime.h>

// LengthRegulator: B=32, P=1024, D=384, T=max_length=3072 (fixed shapes).
// Fused single kernel: each block re-scans its batch's durations (4 KB,
// L2-hot), builds the t->p index map for its T-chunk via O(dur) scatter
// (replaces dependent-latency LDS binary search), then does the coalesced
// float4 row-gather. Second output: output_lengths as float32 in d_out tail.

#define BB 32
#define PP 1024
#define DD 384
#define TT 3072
#define NCHUNK 16
#define CHUNK (TT / NCHUNK)      // 192 output rows per block
#define BLOCK 512                // 8 waves
#define NWAVE (BLOCK / 64)
#define ROW4 (DD / 4)            // 96 float4 per row

__global__ __launch_bounds__(BLOCK) void lr_fused_kernel(
    const float* __restrict__ x, const int* __restrict__ dur,
    float* __restrict__ out, float* __restrict__ len_out)
{
    __shared__ int lidx[CHUNK];
    __shared__ int wtot[NWAVE];

    const int tid  = threadIdx.x;
    const int lane = tid & 63;
    const int wv   = tid >> 6;
    const int b    = blockIdx.y;
    const int lo   = blockIdx.x * CHUNK;

    // ---- block-wide inclusive scan of durations (2 elems/thread, int2) ----
    int2 d = ((const int2*)(dur + b * PP))[tid];
    const int s = d.x + d.y;
    int wsum = s;
    #pragma unroll
    for (int off = 1; off < 64; off <<= 1) {
        int v = __shfl_up(wsum, off, 64);
        if (lane >= off) wsum += v;
    }
    if (lane == 63) wtot[wv] = wsum;
    // init index map while the scan result lands
    for (int i = tid; i < CHUNK; i += BLOCK) lidx[i] = -1;
    __syncthreads();

    int woff = 0, total = 0;
    #pragma unroll
    for (int w = 0; w < NWAVE; ++w) {
        int v = wtot[w];
        if (w < wv) woff += v;
        total += v;
    }
    const int pre    = woff + wsum - s;            // csum before elem 2*tid
    const int outlen = total < TT ? total : TT;

    if (blockIdx.x == 0 && tid == 0) len_out[b] = (float)outlen;

    // ---- scatter: elem p covers t in [csum[p-1], csum[p]) ----
    {
        const int hi = lo + CHUNK;
        int a0 = pre, a1 = pre + d.x, a2 = pre + s;
        int t0 = a0 > lo ? a0 : lo, e0 = a1 < hi ? a1 : hi;
        for (int t = t0; t < e0; ++t) lidx[t - lo] = 2 * tid;
        int t1 = a1 > lo ? a1 : lo, e1 = a2 < hi ? a2 : hi;
        for (int t = t1; t < e1; ++t) lidx[t - lo] = 2 * tid + 1;
    }
    __syncthreads();

    // ---- gather: CHUNK*96 float4 elements, block-strided, coalesced ----
    const float4* __restrict__ x4 = (const float4*)(x + (size_t)b * PP * DD);
    float4* __restrict__ o4 = (float4*)(out + ((size_t)b * TT + lo) * DD);
    #pragma unroll 4
    for (int e = tid; e < CHUNK * ROW4; e += BLOCK) {
        const int t1 = e / ROW4;
        const int c  = e - t1 * ROW4;
        int m = lidx[t1];                 // LDS broadcast (96 threads/row)
        // always issue the load (clamped) so loads batch; select zero after
        float4 v = x4[(m < 0 ? 0 : m) * ROW4 + c];
        if (lo + t1 >= outlen) v = make_float4(0.f, 0.f, 0.f, 0.f);
        o4[e] = v;
    }
}

extern "C" void kernel_launch(void* const* d_in, const int* in_sizes, int n_in,
                              void* d_out, int out_size, void* d_ws, size_t ws_size,
                              hipStream_t stream) {
    const float* x   = (const float*)d_in[0];
    const int*   dur = (const int*)d_in[1];
    // d_in[2] = max_length (device scalar) — value 3072, baked into TT.

    float* out     = (float*)d_out;
    float* len_out = out + (size_t)BB * TT * DD;   // 32 lengths in the tail

    lr_fused_kernel<<<dim3(NCHUNK, BB), BLOCK, 0, stream>>>(x, dur, out, len_out);
}